// Round 1
// baseline (418.142 us; speedup 1.0000x reference)
//
#include <hip/hip_runtime.h>
#include <hip/hip_bf16.h>

// Problem constants
#define M_ROWS  32768   // B*H*W
#define D_DIM   512     // C == latent dim
#define K_CODES 1024
#define HW      1024
#define IMG_STRIDE (D_DIM * HW)   // 524288

// d_out scratch: zh swizzled bf16 (32 MB) lives in the out_q region until the
// final gather overwrites it. idx region (last 128 KB of d_out) is real output.
// ws layout (bytes):
#define WH_OFF   0u          // 1 MB   swizzled cb-hi bf16
#define A_OFF    1048576u    // 128 KB A[i] (numpy-pairwise)
#define W_OFF    1179648u    // 4 KB   W[n]
#define PK_OFF   1183744u    // 128 KB packed candidates/flags
#define PART_OFF 1312768u    // 2.62 MB per-(row,bn) top3 partials
#define WL1_OFF  3934208u    // 128 KB worklist flag==1
#define WL2_OFF  4065280u    // 128 KB worklist flag==2
#define CNT_OFF  4196352u    // 8 B    counters

// 1-term bf16 error: pairwise sigma ~4.3e-5 -> 7.5 sigma = 3.2e-4, plus fp32
// reorder/grid window 1.22e-4 -> 4.4e-4; pad to 5e-4.
#define WINDOW 5.0e-4f

// ---- exact RNE fp32 ops the compiler can't contract/reassociate ----
__device__ __forceinline__ float fmul32(float a, float b) {
  float r; asm volatile("v_mul_f32 %0, %1, %2" : "=v"(r) : "v"(a), "v"(b)); return r;
}
__device__ __forceinline__ float fadd32(float a, float b) {
  float r; asm volatile("v_add_f32 %0, %1, %2" : "=v"(r) : "v"(a), "v"(b)); return r;
}
__device__ __forceinline__ float pair8(const float* r) {
  return fadd32(fadd32(fadd32(r[0], r[1]), fadd32(r[2], r[3])),
                fadd32(fadd32(r[4], r[5]), fadd32(r[6], r[7])));
}

__device__ __forceinline__ unsigned short f2bf(float x) {
  __hip_bfloat16 h = __float2bfloat16(x);
  unsigned short u; __builtin_memcpy(&u, &h, 2); return u;
}

typedef __attribute__((ext_vector_type(8))) short b8;
typedef __attribute__((ext_vector_type(4))) float f4;

__device__ __forceinline__ void gl_lds16(const void* g, void* l) {
  __builtin_amdgcn_global_load_lds(
      (const __attribute__((address_space(1))) unsigned int*)g,
      (__attribute__((address_space(3))) unsigned int*)l, 16, 0, 0);
}

// top-3 tracking (values s1<=s2<=s3; indices for first two; first-index ties)
struct T3 { float s1, s2, s3; int n1, n2; };
__device__ __forceinline__ void t3_merge(T3& a, const T3& bb) {
  T3 x = a, y = bb;
  bool bf = (y.s1 < x.s1) || (y.s1 == x.s1 && y.n1 < x.n1);
  if (bf) { T3 t = x; x = y; y = t; }
  float rs2; int rn2; float rs3;
  bool c2 = (y.s1 < x.s2) || (y.s1 == x.s2 && y.n1 < x.n2);
  if (c2) { rs2 = y.s1; rn2 = y.n1; rs3 = fminf(x.s2, y.s2); }
  else    { rs2 = x.s2; rn2 = x.n2; rs3 = fminf(x.s3, y.s1); }
  a.s1 = x.s1; a.n1 = x.n1; a.s2 = rs2; a.n2 = rn2; a.s3 = rs3;
}

// ---------------------------------------------------------------------------
// Fused: A[i] = np.sum(z^2) (exact numpy fp32 pairwise order, round-3 code
// path untouched) + zh swizzled-bf16 emission. One pass over z.
// zh layout: [kc 16][mb 2048][q 4][m15 16][j 8] bf16.
__global__ __launch_bounds__(256) void vq_prep(const float* __restrict__ z,
                                               float* __restrict__ A,
                                               char* __restrict__ zh_b) {
  __shared__ float zs[4][64 * 68];
  const int wave = threadIdx.x >> 6, t = threadIdx.x & 63;
  const int i0 = blockIdx.x * 256 + wave * 64;
  const int b = i0 >> 10, hw0 = i0 & 1023;
  const float* zbase = z + (size_t)b * IMG_STRIDE + hw0;
  float* zsw = zs[wave];
  const int pos = i0 + t;
  const size_t mbase = (size_t)(pos >> 4) * 1024 + (size_t)(pos & 15) * 16;
  float r8[8], blk[4];
  alignas(16) unsigned short hs[8];
#pragma unroll
  for (int ch = 0; ch < 8; ++ch) {
    __syncthreads();
    {
      const int l = t & 15, j0 = t >> 4;
#pragma unroll
      for (int jj = 0; jj < 16; ++jj) {
        int j = j0 * 16 + jj;
        float4 vv = *(const float4*)(zbase + (size_t)(ch * 64 + j) * HW + 4 * l);
        *(float4*)(zsw + j * 68 + 4 * l) = vv;
      }
    }
    __syncthreads();
#pragma unroll
    for (int j = 0; j < 64; ++j) {
      const int c = ch * 64 + j;
      float v = zsw[j * 68 + t];
      hs[j & 7] = f2bf(v);
      if ((j & 7) == 7) {
        const int kc = c >> 5, q = (c >> 3) & 3;
        *(uint4*)(zh_b + (size_t)kc * 2097152 + q * 256 + mbase) = *(uint4*)hs;
      }
      float pq = fmul32(v, v);
      const int k = c & 7, m = c & 127;
      if (m < 8) r8[k] = pq;
      else       r8[k] = fadd32(r8[k], pq);
      if (m == 127) blk[c >> 7] = pair8(r8);
    }
  }
  A[pos] = fadd32(fadd32(blk[0], blk[1]), fadd32(blk[2], blk[3]));
}

// Fused: W[n] = np.sum(cb^2) (exact pairwise order) + wh swizzled emission.
// wh layout: [kc 16][nb 64][q 4][n15 16][j 8] bf16. Also zeroes counters.
__global__ void vq_prepw(const float* __restrict__ cb, float* __restrict__ W,
                         char* __restrict__ wh_b, int* __restrict__ cnt) {
  if (blockIdx.x == 0 && threadIdx.x < 2) cnt[threadIdx.x] = 0;
  const int n = blockIdx.x * 256 + threadIdx.x;
  const float* wp = cb + (size_t)n * D_DIM;
  const size_t nbase = (size_t)(n >> 4) * 1024 + (size_t)(n & 15) * 16;
  float r8[8], blk[4];
  alignas(16) unsigned short hs[8];
#pragma unroll
  for (int bb = 0; bb < 4; ++bb) {
#pragma unroll
    for (int g = 0; g < 16; ++g) {
      float vv[8];
#pragma unroll
      for (int k = 0; k < 8; ++k) vv[k] = wp[bb * 128 + g * 8 + k];
#pragma unroll
      for (int k = 0; k < 8; ++k) {
        float pq = fmul32(vv[k], vv[k]);
        if (g == 0) r8[k] = pq;
        else        r8[k] = fadd32(r8[k], pq);
        hs[k] = f2bf(vv[k]);
      }
      const int kc = bb * 4 + (g >> 2), q = g & 3;
      *(uint4*)(wh_b + (size_t)kc * 65536 + q * 256 + nbase) = *(uint4*)hs;
    }
    blk[bb] = pair8(r8);
  }
  W[n] = fadd32(fadd32(blk[0], blk[1]), fadd32(blk[2], blk[3]));
}

// ---------------------------------------------------------------------------
// 1-term MFMA scoring: M ~= zh·wh (bf16, fp32 acc); s = W - 2M.
// Block tile 128 pos x 256 n; wave tile 64x128 (4x8 of 16x16x32).
__global__ __launch_bounds__(256, 2) void vq_score(
    const char* __restrict__ zh_b, const char* __restrict__ wh_b,
    const float* __restrict__ Wws, float* __restrict__ part)
{
  __shared__ __align__(16) char smem[24576];  // A 8K | B 16K
  const int tid = threadIdx.x;
  const int lane = tid & 63, wave = tid >> 6;
  const int wr = wave >> 1, wc = wave & 1;
  const int bm = blockIdx.x & 255, bn = blockIdx.x >> 8;
  const int m0 = bm * 128, n0 = bn * 256;

  f4 acc[4][8];
#pragma unroll
  for (int r = 0; r < 4; ++r)
#pragma unroll
    for (int v = 0; v < 8; ++v) acc[r][v] = (f4)(0.0f);

  for (int kc = 0; kc < 16; ++kc) {
    const char* gA = zh_b + (size_t)kc * 2097152 + (size_t)bm * 8192;
    const char* gB = wh_b + (size_t)kc * 65536 + (size_t)bn * 16384;
#pragma unroll
    for (int k = 0; k < 6; ++k) {           // 24 1KB segments, 6 per wave
      int seg = wave + 4 * k;
      const char* g; char* l;
      if (seg < 8) { g = gA + seg * 1024;        l = smem + seg * 1024; }
      else         { g = gB + (seg - 8) * 1024;  l = smem + 8192 + (seg - 8) * 1024; }
      gl_lds16(g + lane * 16, l);
    }
    __syncthreads();
    b8 bh[8];
#pragma unroll
    for (int v = 0; v < 8; ++v)
      bh[v] = *(const b8*)(smem + 8192 + ((wc * 8 + v) << 10) + (lane << 4));
#pragma unroll
    for (int r = 0; r < 4; ++r) {
      b8 ah = *(const b8*)(smem + ((wr * 4 + r) << 10) + (lane << 4));
#pragma unroll
      for (int v = 0; v < 8; ++v)
        acc[r][v] = __builtin_amdgcn_mfma_f32_16x16x32_bf16(ah, bh[v], acc[r][v], 0, 0, 0);
    }
    __syncthreads();
  }

  // epilogue: s = W - 2M; per-row top-3 across this block's 256 n
  const int l15 = lane & 15, quad = lane >> 4;
  float sW[8];
#pragma unroll
  for (int v = 0; v < 8; ++v) sW[v] = Wws[n0 + wc * 128 + v * 16 + l15];

  float* red = (float*)smem;  // [128 rows][2 wc][5]
#pragma unroll
  for (int r = 0; r < 4; ++r) {
#pragma unroll
    for (int reg = 0; reg < 4; ++reg) {
      T3 t; t.s1 = t.s2 = t.s3 = 3.4e38f; t.n1 = 0; t.n2 = 0;
#pragma unroll
      for (int v = 0; v < 8; ++v) {
        float s = fmaf(-2.f, acc[r][v][reg], sW[v]);
        int n = n0 + wc * 128 + v * 16 + l15;
        if (s < t.s1)      { t.s3 = t.s2; t.s2 = t.s1; t.n2 = t.n1; t.s1 = s; t.n1 = n; }
        else if (s < t.s2) { t.s3 = t.s2; t.s2 = s; t.n2 = n; }
        else if (s < t.s3) { t.s3 = s; }
      }
#pragma unroll
      for (int m = 1; m <= 8; m <<= 1) {   // butterfly within 16-lane quad
        T3 o;
        o.s1 = __shfl_xor(t.s1, m); o.s2 = __shfl_xor(t.s2, m); o.s3 = __shfl_xor(t.s3, m);
        o.n1 = __shfl_xor(t.n1, m); o.n2 = __shfl_xor(t.n2, m);
        t3_merge(t, o);
      }
      if (l15 == 0) {
        int row = wr * 64 + r * 16 + quad * 4 + reg;
        float* d = red + (row * 2 + wc) * 5;
        d[0] = t.s1; d[1] = t.s2; d[2] = t.s3; d[3] = (float)t.n1; d[4] = (float)t.n2;
      }
    }
  }
  __syncthreads();
  if (tid < 128) {
    const float* d0 = red + (tid * 2) * 5;
    const float* d1 = red + (tid * 2 + 1) * 5;
    T3 a; a.s1 = d0[0]; a.s2 = d0[1]; a.s3 = d0[2]; a.n1 = (int)d0[3]; a.n2 = (int)d0[4];
    T3 b; b.s1 = d1[0]; b.s2 = d1[1]; b.s3 = d1[2]; b.n1 = (int)d1[3]; b.n2 = (int)d1[4];
    t3_merge(a, b);
    float* p = part + ((size_t)(m0 + tid) * 4 + bn) * 5;
    p[0] = a.s1; p[1] = a.s2; p[2] = a.s3; p[3] = (float)a.n1; p[4] = (float)a.n2;
  }
}

// Combine 4 n-slices per row; write idx, packed candidates, and worklists.
__global__ void vq_comb(const float* __restrict__ part, float* __restrict__ out_idx,
                        unsigned int* __restrict__ pk, int* __restrict__ wl1,
                        int* __restrict__ wl2, int* __restrict__ cnt) {
  int row = blockIdx.x * 256 + threadIdx.x;
  const float* p = part + (size_t)row * 20;
  T3 a; a.s1 = p[0]; a.s2 = p[1]; a.s3 = p[2]; a.n1 = (int)p[3]; a.n2 = (int)p[4];
#pragma unroll
  for (int j = 1; j < 4; ++j) {
    const float* q = p + j * 5;
    T3 b; b.s1 = q[0]; b.s2 = q[1]; b.s3 = q[2]; b.n1 = (int)q[3]; b.n2 = (int)q[4];
    t3_merge(a, b);
  }
  out_idx[row] = (float)a.n1;
  unsigned int f = 0;
  if (a.s2 - a.s1 < WINDOW) f = (a.s3 - a.s1 < WINDOW) ? 2u : 1u;
  pk[row] = (unsigned int)a.n1 | ((unsigned int)a.n2 << 10) | (f << 20);
  if (f == 1u) wl1[atomicAdd(&cnt[0], 1)] = row;
  if (f == 2u) wl2[atomicAdd(&cnt[1], 1)] = row;
}

// fp64 top-2 recheck with reference-exact final combine; one wave per row.
__global__ __launch_bounds__(256) void vq_recheckA(
    const float* __restrict__ z, const float* __restrict__ cb,
    const float* __restrict__ Aws, const float* __restrict__ Wws,
    const unsigned int* __restrict__ pk, const int* __restrict__ wl1,
    const int* __restrict__ cnt, float* __restrict__ out_idx)
{
  const int wave = threadIdx.x >> 6, lane = threadIdx.x & 63;
  const int gw = blockIdx.x * 4 + wave;
  const int c1 = cnt[0];
  for (int i = gw; i < c1; i += 2048) {
    int row = wl1[i];
    unsigned int p = pk[row];
    int n1 = p & 1023, n2 = (p >> 10) & 1023;
    int b = row >> 10, hw = row & 1023;
    const float* zr = z + (size_t)b * IMG_STRIDE + hw;
    const float* c1p = cb + (size_t)n1 * D_DIM;
    const float* c2p = cb + (size_t)n2 * D_DIM;
    double d1 = 0.0, d2 = 0.0;
#pragma unroll
    for (int j = 0; j < 8; ++j) {
      int c = lane + 64 * j;
      double zv = (double)zr[(size_t)c * HW];
      d1 += zv * (double)c1p[c];
      d2 += zv * (double)c2p[c];
    }
#pragma unroll
    for (int off = 32; off > 0; off >>= 1) {
      d1 += __shfl_down(d1, off);
      d2 += __shfl_down(d2, off);
    }
    if (lane == 0) {
      float A_ = Aws[row];
      float e1 = fadd32(fadd32(A_, -2.f * (float)d1), Wws[n1]);
      float e2 = fadd32(fadd32(A_, -2.f * (float)d2), Wws[n2]);
      int win = (e2 < e1 || (e2 == e1 && n2 < n1)) ? n2 : n1;
      out_idx[row] = (float)win;
    }
  }
}

// Full 1024-code fp64 rescan; one block per flag==2 row (rare).
__global__ __launch_bounds__(256) void vq_recheckB(
    const float* __restrict__ z, const float* __restrict__ cb,
    const float* __restrict__ Aws, const float* __restrict__ Wws,
    const int* __restrict__ wl2, const int* __restrict__ cnt,
    float* __restrict__ out_idx)
{
  __shared__ double zd[512];
  __shared__ float rd[256];
  __shared__ int rn[256];
  const int c2 = cnt[1];
  for (int t = blockIdx.x; t < c2; t += 64) {
    int row = wl2[t];
    int b = row >> 10, hw = row & 1023;
    const float* zr = z + (size_t)b * IMG_STRIDE + hw;
    for (int c = threadIdx.x; c < 512; c += 256) zd[c] = (double)zr[(size_t)c * HW];
    __syncthreads();
    float best = 3.4e38f; int bn_ = 0;
    float A_ = Aws[row];
    for (int k = 0; k < 4; ++k) {
      int n = k * 256 + threadIdx.x;
      const float* cn = cb + (size_t)n * D_DIM;
      double dot = 0.0;
#pragma unroll 8
      for (int c = 0; c < 512; ++c) dot += zd[c] * (double)cn[c];
      float e = fadd32(fadd32(A_, -2.f * (float)dot), Wws[n]);
      if (e < best || (e == best && n < bn_)) { best = e; bn_ = n; }
    }
    rd[threadIdx.x] = best; rn[threadIdx.x] = bn_;
    __syncthreads();
    for (int s = 128; s > 0; s >>= 1) {
      if (threadIdx.x < s) {
        float eo = rd[threadIdx.x + s]; int no = rn[threadIdx.x + s];
        if (eo < rd[threadIdx.x] || (eo == rd[threadIdx.x] && no < rn[threadIdx.x])) {
          rd[threadIdx.x] = eo; rn[threadIdx.x] = no;
        }
      }
      __syncthreads();
    }
    if (threadIdx.x == 0) out_idx[row] = (float)rn[0];
    __syncthreads();
  }
}

// Final gather: out_q rows = codebook rows (contiguous; no inverse permute).
// Runs last — overwrites the zh scratch living in the out_q region.
__global__ __launch_bounds__(256) void vq_gather(const float* __restrict__ cb,
                                                 const float* __restrict__ out_idx,
                                                 float* __restrict__ out_q) {
  __shared__ int bidx[64];
  const int i0 = blockIdx.x * 64;
  if (threadIdx.x < 64) bidx[threadIdx.x] = (int)out_idx[i0 + threadIdx.x];
  __syncthreads();
  float* outp = out_q + (size_t)i0 * D_DIM;
  for (int j = 0; j < 32; ++j) {
    int f4i = j * 256 + threadIdx.x;
    int row = f4i >> 7, d4 = f4i & 127;
    float4 vv = *(const float4*)(cb + (size_t)bidx[row] * D_DIM + 4 * d4);
    *(float4*)(outp + 4 * f4i) = vv;
  }
}

extern "C" void kernel_launch(void* const* d_in, const int* in_sizes, int n_in,
                              void* d_out, int out_size, void* d_ws, size_t ws_size,
                              hipStream_t stream) {
  const float* z  = (const float*)d_in[0];
  const float* cb = (const float*)d_in[1];
  float* out_q   = (float*)d_out;
  float* out_idx = (float*)d_out + (size_t)M_ROWS * D_DIM;
  char* zh_b = (char*)d_out;                // out_q region doubles as zh scratch
  char* ws = (char*)d_ws;
  char* wh_b = ws + WH_OFF;
  float* Aws = (float*)(ws + A_OFF);
  float* Wws = (float*)(ws + W_OFF);
  unsigned int* pk = (unsigned int*)(ws + PK_OFF);
  float* part = (float*)(ws + PART_OFF);
  int* wl1 = (int*)(ws + WL1_OFF);
  int* wl2 = (int*)(ws + WL2_OFF);
  int* cnt = (int*)(ws + CNT_OFF);

  vq_prep    <<<128, 256, 0, stream>>>(z, Aws, zh_b);
  vq_prepw   <<<4, 256, 0, stream>>>(cb, Wws, wh_b, cnt);
  vq_score   <<<1024, 256, 0, stream>>>(zh_b, wh_b, Wws, part);
  vq_comb    <<<128, 256, 0, stream>>>(part, out_idx, pk, wl1, wl2, cnt);
  vq_recheckA<<<512, 256, 0, stream>>>(z, cb, Aws, Wws, pk, wl1, cnt, out_idx);
  vq_recheckB<<<64, 256, 0, stream>>>(z, cb, Aws, Wws, wl2, cnt, out_idx);
  vq_gather  <<<512, 256, 0, stream>>>(cb, out_idx, out_q);
}

// Round 2
// 390.199 us; speedup vs baseline: 1.0716x; 1.0716x over previous
//
#include <hip/hip_runtime.h>
#include <hip/hip_bf16.h>

// Problem constants
#define M_ROWS  32768   // B*H*W
#define D_DIM   512     // C == latent dim
#define K_CODES 1024
#define HW      1024
#define IMG_STRIDE (D_DIM * HW)   // 524288

// d_out scratch: zh swizzled bf16 (32 MB) lives in the out_q region until the
// final gather overwrites it. idx region (last 128 KB of d_out) is real output.
// ws layout (bytes):
#define WH_OFF   0u          // 1 MB   swizzled cb-hi bf16
#define A_OFF    1048576u    // 128 KB A[i] (numpy-pairwise)
#define W_OFF    1179648u    // 4 KB   W[n]
#define PK_OFF   1183744u    // 128 KB packed candidates/flags
#define PART_OFF 1312768u    // 2.62 MB per-(row,bn) top3 partials
#define WL1_OFF  3934208u    // 128 KB worklist flag==1
#define WL2_OFF  4065280u    // 128 KB worklist flag==2
#define CNT_OFF  4196352u    // 8 B    counters

// 1-term bf16 error: pairwise sigma ~4.3e-5 -> 7.5 sigma = 3.2e-4, plus fp32
// reorder/grid window 1.22e-4 -> 4.4e-4; pad to 5e-4.
#define WINDOW 5.0e-4f

// ---- exact RNE fp32 ops the compiler can't contract/reassociate ----
__device__ __forceinline__ float fmul32(float a, float b) {
  float r; asm volatile("v_mul_f32 %0, %1, %2" : "=v"(r) : "v"(a), "v"(b)); return r;
}
__device__ __forceinline__ float fadd32(float a, float b) {
  float r; asm volatile("v_add_f32 %0, %1, %2" : "=v"(r) : "v"(a), "v"(b)); return r;
}
__device__ __forceinline__ float pair8(const float* r) {
  return fadd32(fadd32(fadd32(r[0], r[1]), fadd32(r[2], r[3])),
                fadd32(fadd32(r[4], r[5]), fadd32(r[6], r[7])));
}

__device__ __forceinline__ unsigned short f2bf(float x) {
  __hip_bfloat16 h = __float2bfloat16(x);
  unsigned short u; __builtin_memcpy(&u, &h, 2); return u;
}

typedef __attribute__((ext_vector_type(8))) short b8;
typedef __attribute__((ext_vector_type(4))) float f4;

__device__ __forceinline__ void gl_lds16(const void* g, void* l) {
  __builtin_amdgcn_global_load_lds(
      (const __attribute__((address_space(1))) unsigned int*)g,
      (__attribute__((address_space(3))) unsigned int*)l, 16, 0, 0);
}

// top-3 tracking (values s1<=s2<=s3; indices for first two; first-index ties)
struct T3 { float s1, s2, s3; int n1, n2; };
__device__ __forceinline__ void t3_merge(T3& a, const T3& bb) {
  T3 x = a, y = bb;
  bool bf = (y.s1 < x.s1) || (y.s1 == x.s1 && y.n1 < x.n1);
  if (bf) { T3 t = x; x = y; y = t; }
  float rs2; int rn2; float rs3;
  bool c2 = (y.s1 < x.s2) || (y.s1 == x.s2 && y.n1 < x.n2);
  if (c2) { rs2 = y.s1; rn2 = y.n1; rs3 = fminf(x.s2, y.s2); }
  else    { rs2 = x.s2; rn2 = x.n2; rs3 = fminf(x.s3, y.s1); }
  a.s1 = x.s1; a.n1 = x.n1; a.s2 = rs2; a.n2 = rn2; a.s3 = rs3;
}

// ---------------------------------------------------------------------------
// Fused: A[i] = np.sum(z^2) (exact numpy fp32 pairwise order, round-3 code
// path untouched) + zh swizzled-bf16 emission. One pass over z.
// zh layout: [kc 16][mb 2048][q 4][m15 16][j 8] bf16.
__global__ __launch_bounds__(256) void vq_prep(const float* __restrict__ z,
                                               float* __restrict__ A,
                                               char* __restrict__ zh_b) {
  __shared__ float zs[4][64 * 68];
  const int wave = threadIdx.x >> 6, t = threadIdx.x & 63;
  const int i0 = blockIdx.x * 256 + wave * 64;
  const int b = i0 >> 10, hw0 = i0 & 1023;
  const float* zbase = z + (size_t)b * IMG_STRIDE + hw0;
  float* zsw = zs[wave];
  const int pos = i0 + t;
  const size_t mbase = (size_t)(pos >> 4) * 1024 + (size_t)(pos & 15) * 16;
  float r8[8], blk[4];
  alignas(16) unsigned short hs[8];
#pragma unroll
  for (int ch = 0; ch < 8; ++ch) {
    __syncthreads();
    {
      const int l = t & 15, j0 = t >> 4;
#pragma unroll
      for (int jj = 0; jj < 16; ++jj) {
        int j = j0 * 16 + jj;
        float4 vv = *(const float4*)(zbase + (size_t)(ch * 64 + j) * HW + 4 * l);
        *(float4*)(zsw + j * 68 + 4 * l) = vv;
      }
    }
    __syncthreads();
#pragma unroll
    for (int j = 0; j < 64; ++j) {
      const int c = ch * 64 + j;
      float v = zsw[j * 68 + t];
      hs[j & 7] = f2bf(v);
      if ((j & 7) == 7) {
        const int kc = c >> 5, q = (c >> 3) & 3;
        *(uint4*)(zh_b + (size_t)kc * 2097152 + q * 256 + mbase) = *(uint4*)hs;
      }
      float pq = fmul32(v, v);
      const int k = c & 7, m = c & 127;
      if (m < 8) r8[k] = pq;
      else       r8[k] = fadd32(r8[k], pq);
      if (m == 127) blk[c >> 7] = pair8(r8);
    }
  }
  A[pos] = fadd32(fadd32(blk[0], blk[1]), fadd32(blk[2], blk[3]));
}

// Fused: W[n] = np.sum(cb^2) (exact pairwise order) + wh swizzled emission.
// wh layout: [kc 16][nb 64][q 4][n15 16][j 8] bf16. Also zeroes counters.
__global__ void vq_prepw(const float* __restrict__ cb, float* __restrict__ W,
                         char* __restrict__ wh_b, int* __restrict__ cnt) {
  if (blockIdx.x == 0 && threadIdx.x < 2) cnt[threadIdx.x] = 0;
  const int n = blockIdx.x * 256 + threadIdx.x;
  const float* wp = cb + (size_t)n * D_DIM;
  const size_t nbase = (size_t)(n >> 4) * 1024 + (size_t)(n & 15) * 16;
  float r8[8], blk[4];
  alignas(16) unsigned short hs[8];
#pragma unroll
  for (int bb = 0; bb < 4; ++bb) {
#pragma unroll
    for (int g = 0; g < 16; ++g) {
      float vv[8];
#pragma unroll
      for (int k = 0; k < 8; ++k) vv[k] = wp[bb * 128 + g * 8 + k];
#pragma unroll
      for (int k = 0; k < 8; ++k) {
        float pq = fmul32(vv[k], vv[k]);
        if (g == 0) r8[k] = pq;
        else        r8[k] = fadd32(r8[k], pq);
        hs[k] = f2bf(vv[k]);
      }
      const int kc = bb * 4 + (g >> 2), q = g & 3;
      *(uint4*)(wh_b + (size_t)kc * 65536 + q * 256 + nbase) = *(uint4*)hs;
    }
    blk[bb] = pair8(r8);
  }
  W[n] = fadd32(fadd32(blk[0], blk[1]), fadd32(blk[2], blk[3]));
}

// ---------------------------------------------------------------------------
// 1-term MFMA scoring: M ~= zh·wh (bf16, fp32 acc); s = W - 2M.
// Block tile 128 pos x 256 n; wave tile 64x128 (4x8 of 16x16x32).
__global__ __launch_bounds__(256, 2) void vq_score(
    const char* __restrict__ zh_b, const char* __restrict__ wh_b,
    const float* __restrict__ Wws, float* __restrict__ part)
{
  __shared__ __align__(16) char smem[24576];  // A 8K | B 16K
  const int tid = threadIdx.x;
  const int lane = tid & 63, wave = tid >> 6;
  const int wr = wave >> 1, wc = wave & 1;
  const int bm = blockIdx.x & 255, bn = blockIdx.x >> 8;
  const int m0 = bm * 128, n0 = bn * 256;

  f4 acc[4][8];
#pragma unroll
  for (int r = 0; r < 4; ++r)
#pragma unroll
    for (int v = 0; v < 8; ++v) acc[r][v] = (f4)(0.0f);

  for (int kc = 0; kc < 16; ++kc) {
    const char* gA = zh_b + (size_t)kc * 2097152 + (size_t)bm * 8192;
    const char* gB = wh_b + (size_t)kc * 65536 + (size_t)bn * 16384;
#pragma unroll
    for (int k = 0; k < 6; ++k) {           // 24 1KB segments, 6 per wave
      int seg = wave + 4 * k;
      const char* g; char* l;
      if (seg < 8) { g = gA + seg * 1024;        l = smem + seg * 1024; }
      else         { g = gB + (seg - 8) * 1024;  l = smem + 8192 + (seg - 8) * 1024; }
      gl_lds16(g + lane * 16, l);
    }
    __syncthreads();
    b8 bh[8];
#pragma unroll
    for (int v = 0; v < 8; ++v)
      bh[v] = *(const b8*)(smem + 8192 + ((wc * 8 + v) << 10) + (lane << 4));
#pragma unroll
    for (int r = 0; r < 4; ++r) {
      b8 ah = *(const b8*)(smem + ((wr * 4 + r) << 10) + (lane << 4));
#pragma unroll
      for (int v = 0; v < 8; ++v)
        acc[r][v] = __builtin_amdgcn_mfma_f32_16x16x32_bf16(ah, bh[v], acc[r][v], 0, 0, 0);
    }
    __syncthreads();
  }

  // epilogue: s = W - 2M; per-row top-3 across this block's 256 n
  const int l15 = lane & 15, quad = lane >> 4;
  float sW[8];
#pragma unroll
  for (int v = 0; v < 8; ++v) sW[v] = Wws[n0 + wc * 128 + v * 16 + l15];

  float* red = (float*)smem;  // [128 rows][2 wc][5]
#pragma unroll
  for (int r = 0; r < 4; ++r) {
#pragma unroll
    for (int reg = 0; reg < 4; ++reg) {
      T3 t; t.s1 = t.s2 = t.s3 = 3.4e38f; t.n1 = 0; t.n2 = 0;
#pragma unroll
      for (int v = 0; v < 8; ++v) {
        float s = fmaf(-2.f, acc[r][v][reg], sW[v]);
        int n = n0 + wc * 128 + v * 16 + l15;
        if (s < t.s1)      { t.s3 = t.s2; t.s2 = t.s1; t.n2 = t.n1; t.s1 = s; t.n1 = n; }
        else if (s < t.s2) { t.s3 = t.s2; t.s2 = s; t.n2 = n; }
        else if (s < t.s3) { t.s3 = s; }
      }
#pragma unroll
      for (int m = 1; m <= 8; m <<= 1) {   // butterfly within 16-lane quad
        T3 o;
        o.s1 = __shfl_xor(t.s1, m); o.s2 = __shfl_xor(t.s2, m); o.s3 = __shfl_xor(t.s3, m);
        o.n1 = __shfl_xor(t.n1, m); o.n2 = __shfl_xor(t.n2, m);
        t3_merge(t, o);
      }
      if (l15 == 0) {
        int row = wr * 64 + r * 16 + quad * 4 + reg;
        float* d = red + (row * 2 + wc) * 5;
        d[0] = t.s1; d[1] = t.s2; d[2] = t.s3; d[3] = (float)t.n1; d[4] = (float)t.n2;
      }
    }
  }
  __syncthreads();
  if (tid < 128) {
    const float* d0 = red + (tid * 2) * 5;
    const float* d1 = red + (tid * 2 + 1) * 5;
    T3 a; a.s1 = d0[0]; a.s2 = d0[1]; a.s3 = d0[2]; a.n1 = (int)d0[3]; a.n2 = (int)d0[4];
    T3 b; b.s1 = d1[0]; b.s2 = d1[1]; b.s3 = d1[2]; b.n1 = (int)d1[3]; b.n2 = (int)d1[4];
    t3_merge(a, b);
    float* p = part + ((size_t)(m0 + tid) * 4 + bn) * 5;
    p[0] = a.s1; p[1] = a.s2; p[2] = a.s3; p[3] = (float)a.n1; p[4] = (float)a.n2;
  }
}

// Combine 4 n-slices per row; write idx, packed candidates, and worklists.
__global__ void vq_comb(const float* __restrict__ part, float* __restrict__ out_idx,
                        unsigned int* __restrict__ pk, int* __restrict__ wl1,
                        int* __restrict__ wl2, int* __restrict__ cnt) {
  int row = blockIdx.x * 256 + threadIdx.x;
  const float* p = part + (size_t)row * 20;
  T3 a; a.s1 = p[0]; a.s2 = p[1]; a.s3 = p[2]; a.n1 = (int)p[3]; a.n2 = (int)p[4];
#pragma unroll
  for (int j = 1; j < 4; ++j) {
    const float* q = p + j * 5;
    T3 b; b.s1 = q[0]; b.s2 = q[1]; b.s3 = q[2]; b.n1 = (int)q[3]; b.n2 = (int)q[4];
    t3_merge(a, b);
  }
  out_idx[row] = (float)a.n1;
  unsigned int f = 0;
  if (a.s2 - a.s1 < WINDOW) f = (a.s3 - a.s1 < WINDOW) ? 2u : 1u;
  pk[row] = (unsigned int)a.n1 | ((unsigned int)a.n2 << 10) | (f << 20);
  if (f == 1u) wl1[atomicAdd(&cnt[0], 1)] = row;
  if (f == 2u) wl2[atomicAdd(&cnt[1], 1)] = row;
}

// fp64 top-2 recheck with reference-exact final combine; one wave per row.
__global__ __launch_bounds__(256) void vq_recheckA(
    const float* __restrict__ z, const float* __restrict__ cb,
    const float* __restrict__ Aws, const float* __restrict__ Wws,
    const unsigned int* __restrict__ pk, const int* __restrict__ wl1,
    const int* __restrict__ cnt, float* __restrict__ out_idx)
{
  const int wave = threadIdx.x >> 6, lane = threadIdx.x & 63;
  const int gw = blockIdx.x * 4 + wave;
  const int c1 = cnt[0];
  for (int i = gw; i < c1; i += 2048) {
    int row = wl1[i];
    unsigned int p = pk[row];
    int n1 = p & 1023, n2 = (p >> 10) & 1023;
    int b = row >> 10, hw = row & 1023;
    const float* zr = z + (size_t)b * IMG_STRIDE + hw;
    const float* c1p = cb + (size_t)n1 * D_DIM;
    const float* c2p = cb + (size_t)n2 * D_DIM;
    double d1 = 0.0, d2 = 0.0;
#pragma unroll
    for (int j = 0; j < 8; ++j) {
      int c = lane + 64 * j;
      double zv = (double)zr[(size_t)c * HW];
      d1 += zv * (double)c1p[c];
      d2 += zv * (double)c2p[c];
    }
#pragma unroll
    for (int off = 32; off > 0; off >>= 1) {
      d1 += __shfl_down(d1, off);
      d2 += __shfl_down(d2, off);
    }
    if (lane == 0) {
      float A_ = Aws[row];
      float e1 = fadd32(fadd32(A_, -2.f * (float)d1), Wws[n1]);
      float e2 = fadd32(fadd32(A_, -2.f * (float)d2), Wws[n2]);
      int win = (e2 < e1 || (e2 == e1 && n2 < n1)) ? n2 : n1;
      out_idx[row] = (float)win;
    }
  }
}

// Full 1024-code fp64 rescan for flag==2 rows.
// R1 rewrite: was 131 µs at 2.3% occupancy / 2.5% VALUBusy — 64 blocks with
// ~5 serial rows each, scalar cb loads, single serial fp64 FMA chain.
// Now: 512 blocks (1 row/block typical), float4 cb loads, 4 independent
// fp64 accumulators. fp64 reassoc error ~5e-16 << fp32 ulp (~1e-9) of the
// scores, so the (float)dot rounding and all tie rules are unaffected.
__global__ __launch_bounds__(256) void vq_recheckB(
    const float* __restrict__ z, const float* __restrict__ cb,
    const float* __restrict__ Aws, const float* __restrict__ Wws,
    const int* __restrict__ wl2, const int* __restrict__ cnt,
    float* __restrict__ out_idx)
{
  __shared__ double zd[512];
  __shared__ float rd[256];
  __shared__ int rn[256];
  const int c2 = cnt[1];
  for (int t = blockIdx.x; t < c2; t += gridDim.x) {
    int row = wl2[t];
    int b = row >> 10, hw = row & 1023;
    const float* zr = z + (size_t)b * IMG_STRIDE + hw;
    for (int c = threadIdx.x; c < 512; c += 256) zd[c] = (double)zr[(size_t)c * HW];
    __syncthreads();
    float best = 3.4e38f; int bn_ = 0;
    float A_ = Aws[row];
    for (int k = 0; k < 4; ++k) {
      int n = k * 256 + threadIdx.x;
      const float* cn = cb + (size_t)n * D_DIM;
      double a0 = 0.0, a1 = 0.0, a2 = 0.0, a3 = 0.0;
#pragma unroll 8
      for (int c4 = 0; c4 < 128; ++c4) {
        float4 w4 = *(const float4*)(cn + 4 * c4);
        a0 += zd[4 * c4 + 0] * (double)w4.x;   // zd reads are broadcast (all
        a1 += zd[4 * c4 + 1] * (double)w4.y;   // lanes same addr) — no bank
        a2 += zd[4 * c4 + 2] * (double)w4.z;   // conflicts.
        a3 += zd[4 * c4 + 3] * (double)w4.w;
      }
      double dot = (a0 + a1) + (a2 + a3);
      float e = fadd32(fadd32(A_, -2.f * (float)dot), Wws[n]);
      if (e < best || (e == best && n < bn_)) { best = e; bn_ = n; }
    }
    rd[threadIdx.x] = best; rn[threadIdx.x] = bn_;
    __syncthreads();
    for (int s = 128; s > 0; s >>= 1) {
      if (threadIdx.x < s) {
        float eo = rd[threadIdx.x + s]; int no = rn[threadIdx.x + s];
        if (eo < rd[threadIdx.x] || (eo == rd[threadIdx.x] && no < rn[threadIdx.x])) {
          rd[threadIdx.x] = eo; rn[threadIdx.x] = no;
        }
      }
      __syncthreads();
    }
    if (threadIdx.x == 0) out_idx[row] = (float)rn[0];
    __syncthreads();
  }
}

// Final gather: out_q rows = codebook rows (contiguous; no inverse permute).
// Runs last — overwrites the zh scratch living in the out_q region.
__global__ __launch_bounds__(256) void vq_gather(const float* __restrict__ cb,
                                                 const float* __restrict__ out_idx,
                                                 float* __restrict__ out_q) {
  __shared__ int bidx[64];
  const int i0 = blockIdx.x * 64;
  if (threadIdx.x < 64) bidx[threadIdx.x] = (int)out_idx[i0 + threadIdx.x];
  __syncthreads();
  float* outp = out_q + (size_t)i0 * D_DIM;
  for (int j = 0; j < 32; ++j) {
    int f4i = j * 256 + threadIdx.x;
    int row = f4i >> 7, d4 = f4i & 127;
    float4 vv = *(const float4*)(cb + (size_t)bidx[row] * D_DIM + 4 * d4);
    *(float4*)(outp + 4 * f4i) = vv;
  }
}

extern "C" void kernel_launch(void* const* d_in, const int* in_sizes, int n_in,
                              void* d_out, int out_size, void* d_ws, size_t ws_size,
                              hipStream_t stream) {
  const float* z  = (const float*)d_in[0];
  const float* cb = (const float*)d_in[1];
  float* out_q   = (float*)d_out;
  float* out_idx = (float*)d_out + (size_t)M_ROWS * D_DIM;
  char* zh_b = (char*)d_out;                // out_q region doubles as zh scratch
  char* ws = (char*)d_ws;
  char* wh_b = ws + WH_OFF;
  float* Aws = (float*)(ws + A_OFF);
  float* Wws = (float*)(ws + W_OFF);
  unsigned int* pk = (unsigned int*)(ws + PK_OFF);
  float* part = (float*)(ws + PART_OFF);
  int* wl1 = (int*)(ws + WL1_OFF);
  int* wl2 = (int*)(ws + WL2_OFF);
  int* cnt = (int*)(ws + CNT_OFF);

  vq_prep    <<<128, 256, 0, stream>>>(z, Aws, zh_b);
  vq_prepw   <<<4, 256, 0, stream>>>(cb, Wws, wh_b, cnt);
  vq_score   <<<1024, 256, 0, stream>>>(zh_b, wh_b, Wws, part);
  vq_comb    <<<128, 256, 0, stream>>>(part, out_idx, pk, wl1, wl2, cnt);
  vq_recheckA<<<512, 256, 0, stream>>>(z, cb, Aws, Wws, pk, wl1, cnt, out_idx);
  vq_recheckB<<<512, 256, 0, stream>>>(z, cb, Aws, Wws, wl2, cnt, out_idx);
  vq_gather  <<<512, 256, 0, stream>>>(cb, out_idx, out_q);
}

// Round 3
// 376.119 us; speedup vs baseline: 1.1117x; 1.0374x over previous
//
#include <hip/hip_runtime.h>
#include <hip/hip_bf16.h>

// Problem constants
#define M_ROWS  32768   // B*H*W
#define D_DIM   512     // C == latent dim
#define K_CODES 1024
#define HW      1024
#define IMG_STRIDE (D_DIM * HW)   // 524288

// d_out scratch: zh swizzled bf16 (32 MB) lives in the out_q region until the
// final gather overwrites it. idx region (last 128 KB of d_out) is real output.
// ws layout (bytes):
#define WH_OFF   0u          // 1 MB   swizzled cb-hi bf16
#define A_OFF    1048576u    // 128 KB A[i] (numpy-pairwise)
#define W_OFF    1179648u    // 4 KB   W[n]
#define PK_OFF   1183744u    // 128 KB packed candidates/flags
#define PART_OFF 1312768u    // 2.62 MB per-(row,bn) top3 partials
#define WL1_OFF  3934208u    // 128 KB worklist flag==1
#define WL2_OFF  4065280u    // 128 KB worklist flag==2
#define CNT_OFF  4196352u    // 8 B    counters

// 1-term bf16 error: pairwise sigma ~4.3e-5 -> 7.5 sigma = 3.2e-4, plus fp32
// reorder/grid window 1.22e-4 -> 4.4e-4; pad to 5e-4.
#define WINDOW 5.0e-4f

// ---- exact RNE fp32 ops the compiler can't contract/reassociate ----
__device__ __forceinline__ float fmul32(float a, float b) {
  float r; asm volatile("v_mul_f32 %0, %1, %2" : "=v"(r) : "v"(a), "v"(b)); return r;
}
__device__ __forceinline__ float fadd32(float a, float b) {
  float r; asm volatile("v_add_f32 %0, %1, %2" : "=v"(r) : "v"(a), "v"(b)); return r;
}
__device__ __forceinline__ float pair8(const float* r) {
  return fadd32(fadd32(fadd32(r[0], r[1]), fadd32(r[2], r[3])),
                fadd32(fadd32(r[4], r[5]), fadd32(r[6], r[7])));
}

__device__ __forceinline__ unsigned short f2bf(float x) {
  __hip_bfloat16 h = __float2bfloat16(x);
  unsigned short u; __builtin_memcpy(&u, &h, 2); return u;
}

typedef __attribute__((ext_vector_type(8))) short b8;
typedef __attribute__((ext_vector_type(4))) float f4;

__device__ __forceinline__ void gl_lds16(const void* g, void* l) {
  __builtin_amdgcn_global_load_lds(
      (const __attribute__((address_space(1))) unsigned int*)g,
      (__attribute__((address_space(3))) unsigned int*)l, 16, 0, 0);
}

// top-3 tracking (values s1<=s2<=s3; indices for first two; first-index ties)
struct T3 { float s1, s2, s3; int n1, n2; };
__device__ __forceinline__ void t3_merge(T3& a, const T3& bb) {
  T3 x = a, y = bb;
  bool bf = (y.s1 < x.s1) || (y.s1 == x.s1 && y.n1 < x.n1);
  if (bf) { T3 t = x; x = y; y = t; }
  float rs2; int rn2; float rs3;
  bool c2 = (y.s1 < x.s2) || (y.s1 == x.s2 && y.n1 < x.n2);
  if (c2) { rs2 = y.s1; rn2 = y.n1; rs3 = fminf(x.s2, y.s2); }
  else    { rs2 = x.s2; rn2 = x.n2; rs3 = fminf(x.s3, y.s1); }
  a.s1 = x.s1; a.n1 = x.n1; a.s2 = rs2; a.n2 = rn2; a.s3 = rs3;
}

// ---------------------------------------------------------------------------
// Fused: A[i] = np.sum(z^2) (exact numpy fp32 pairwise order, round-3 code
// path untouched) + zh swizzled-bf16 emission. One pass over z.
// zh layout: [kc 16][mb 2048][q 4][m15 16][j 8] bf16.
__global__ __launch_bounds__(256) void vq_prep(const float* __restrict__ z,
                                               float* __restrict__ A,
                                               char* __restrict__ zh_b) {
  __shared__ float zs[4][64 * 68];
  const int wave = threadIdx.x >> 6, t = threadIdx.x & 63;
  const int i0 = blockIdx.x * 256 + wave * 64;
  const int b = i0 >> 10, hw0 = i0 & 1023;
  const float* zbase = z + (size_t)b * IMG_STRIDE + hw0;
  float* zsw = zs[wave];
  const int pos = i0 + t;
  const size_t mbase = (size_t)(pos >> 4) * 1024 + (size_t)(pos & 15) * 16;
  float r8[8], blk[4];
  alignas(16) unsigned short hs[8];
#pragma unroll
  for (int ch = 0; ch < 8; ++ch) {
    __syncthreads();
    {
      const int l = t & 15, j0 = t >> 4;
#pragma unroll
      for (int jj = 0; jj < 16; ++jj) {
        int j = j0 * 16 + jj;
        float4 vv = *(const float4*)(zbase + (size_t)(ch * 64 + j) * HW + 4 * l);
        *(float4*)(zsw + j * 68 + 4 * l) = vv;
      }
    }
    __syncthreads();
#pragma unroll
    for (int j = 0; j < 64; ++j) {
      const int c = ch * 64 + j;
      float v = zsw[j * 68 + t];
      hs[j & 7] = f2bf(v);
      if ((j & 7) == 7) {
        const int kc = c >> 5, q = (c >> 3) & 3;
        *(uint4*)(zh_b + (size_t)kc * 2097152 + q * 256 + mbase) = *(uint4*)hs;
      }
      float pq = fmul32(v, v);
      const int k = c & 7, m = c & 127;
      if (m < 8) r8[k] = pq;
      else       r8[k] = fadd32(r8[k], pq);
      if (m == 127) blk[c >> 7] = pair8(r8);
    }
  }
  A[pos] = fadd32(fadd32(blk[0], blk[1]), fadd32(blk[2], blk[3]));
}

// Fused: W[n] = np.sum(cb^2) (exact pairwise order) + wh swizzled emission.
// wh layout: [kc 16][nb 64][q 4][n15 16][j 8] bf16. Also zeroes counters.
__global__ void vq_prepw(const float* __restrict__ cb, float* __restrict__ W,
                         char* __restrict__ wh_b, int* __restrict__ cnt) {
  if (blockIdx.x == 0 && threadIdx.x < 2) cnt[threadIdx.x] = 0;
  const int n = blockIdx.x * 256 + threadIdx.x;
  const float* wp = cb + (size_t)n * D_DIM;
  const size_t nbase = (size_t)(n >> 4) * 1024 + (size_t)(n & 15) * 16;
  float r8[8], blk[4];
  alignas(16) unsigned short hs[8];
#pragma unroll
  for (int bb = 0; bb < 4; ++bb) {
#pragma unroll
    for (int g = 0; g < 16; ++g) {
      float vv[8];
#pragma unroll
      for (int k = 0; k < 8; ++k) vv[k] = wp[bb * 128 + g * 8 + k];
#pragma unroll
      for (int k = 0; k < 8; ++k) {
        float pq = fmul32(vv[k], vv[k]);
        if (g == 0) r8[k] = pq;
        else        r8[k] = fadd32(r8[k], pq);
        hs[k] = f2bf(vv[k]);
      }
      const int kc = bb * 4 + (g >> 2), q = g & 3;
      *(uint4*)(wh_b + (size_t)kc * 65536 + q * 256 + nbase) = *(uint4*)hs;
    }
    blk[bb] = pair8(r8);
  }
  W[n] = fadd32(fadd32(blk[0], blk[1]), fadd32(blk[2], blk[3]));
}

// ---------------------------------------------------------------------------
// 1-term MFMA scoring: M ~= zh·wh (bf16, fp32 acc); s = W - 2M.
// Block tile 128 pos x 256 n; wave tile 64x128 (4x8 of 16x16x32).
// R2: double-buffered LDS (catalog T3 minimum 2-phase). Old 1-phase exposed
// the full stage latency at each barrier (MfmaUtil 10%, VALUBusy 22%,
// occupancy reg-capped at 2 blocks/CU so TLP couldn't fill it). Now
// STAGE(kc+1) is issued before compute(kc); one __syncthreads per iter.
__global__ __launch_bounds__(256, 2) void vq_score(
    const char* __restrict__ zh_b, const char* __restrict__ wh_b,
    const float* __restrict__ Wws, float* __restrict__ part)
{
  __shared__ __align__(16) char smem[49152];  // 2 x (A 8K | B 16K)
  const int tid = threadIdx.x;
  const int lane = tid & 63, wave = tid >> 6;
  const int wr = wave >> 1, wc = wave & 1;
  const int bm = blockIdx.x & 255, bn = blockIdx.x >> 8;
  const int m0 = bm * 128, n0 = bn * 256;

  f4 acc[4][8];
#pragma unroll
  for (int r = 0; r < 4; ++r)
#pragma unroll
    for (int v = 0; v < 8; ++v) acc[r][v] = (f4)(0.0f);

  const char* gA0 = zh_b + (size_t)bm * 8192;
  const char* gB0 = wh_b + (size_t)bn * 16384;

  // stage one kc-tile (24 KB: A 8K | B 16K) into buffer sb
  auto STAGE = [&](int kc, char* sb) {
    const char* gA = gA0 + (size_t)kc * 2097152;
    const char* gB = gB0 + (size_t)kc * 65536;
#pragma unroll
    for (int k = 0; k < 6; ++k) {           // 24 1KB segments, 6 per wave
      int seg = wave + 4 * k;
      const char* g; char* l;
      if (seg < 8) { g = gA + seg * 1024;        l = sb + seg * 1024; }
      else         { g = gB + (seg - 8) * 1024;  l = sb + 8192 + (seg - 8) * 1024; }
      gl_lds16(g + lane * 16, l);
    }
  };

  STAGE(0, smem);
  __syncthreads();                          // drains vmcnt(0): buf0 ready

  for (int kc = 0; kc < 16; ++kc) {
    char* cur = smem + ((kc & 1) ? 24576 : 0);
    char* nxt = smem + ((kc & 1) ? 0 : 24576);
    if (kc < 15) STAGE(kc + 1, nxt);        // prefetch overlaps compute below
    b8 bh[8];
#pragma unroll
    for (int v = 0; v < 8; ++v)
      bh[v] = *(const b8*)(cur + 8192 + ((wc * 8 + v) << 10) + (lane << 4));
#pragma unroll
    for (int r = 0; r < 4; ++r) {
      b8 ah = *(const b8*)(cur + ((wr * 4 + r) << 10) + (lane << 4));
#pragma unroll
      for (int v = 0; v < 8; ++v)
        acc[r][v] = __builtin_amdgcn_mfma_f32_16x16x32_bf16(ah, bh[v], acc[r][v], 0, 0, 0);
    }
    __syncthreads();                        // one barrier/iter: prefetch landed,
  }                                         // all reads of cur done -> swap

  // epilogue: s = W - 2M; per-row top-3 across this block's 256 n
  const int l15 = lane & 15, quad = lane >> 4;
  float sW[8];
#pragma unroll
  for (int v = 0; v < 8; ++v) sW[v] = Wws[n0 + wc * 128 + v * 16 + l15];

  float* red = (float*)smem;  // [128 rows][2 wc][5]
#pragma unroll
  for (int r = 0; r < 4; ++r) {
#pragma unroll
    for (int reg = 0; reg < 4; ++reg) {
      T3 t; t.s1 = t.s2 = t.s3 = 3.4e38f; t.n1 = 0; t.n2 = 0;
#pragma unroll
      for (int v = 0; v < 8; ++v) {
        float s = fmaf(-2.f, acc[r][v][reg], sW[v]);
        int n = n0 + wc * 128 + v * 16 + l15;
        if (s < t.s1)      { t.s3 = t.s2; t.s2 = t.s1; t.n2 = t.n1; t.s1 = s; t.n1 = n; }
        else if (s < t.s2) { t.s3 = t.s2; t.s2 = s; t.n2 = n; }
        else if (s < t.s3) { t.s3 = s; }
      }
#pragma unroll
      for (int m = 1; m <= 8; m <<= 1) {   // butterfly within 16-lane quad
        T3 o;
        o.s1 = __shfl_xor(t.s1, m); o.s2 = __shfl_xor(t.s2, m); o.s3 = __shfl_xor(t.s3, m);
        o.n1 = __shfl_xor(t.n1, m); o.n2 = __shfl_xor(t.n2, m);
        t3_merge(t, o);
      }
      if (l15 == 0) {
        int row = wr * 64 + r * 16 + quad * 4 + reg;
        float* d = red + (row * 2 + wc) * 5;
        d[0] = t.s1; d[1] = t.s2; d[2] = t.s3; d[3] = (float)t.n1; d[4] = (float)t.n2;
      }
    }
  }
  __syncthreads();
  if (tid < 128) {
    const float* d0 = red + (tid * 2) * 5;
    const float* d1 = red + (tid * 2 + 1) * 5;
    T3 a; a.s1 = d0[0]; a.s2 = d0[1]; a.s3 = d0[2]; a.n1 = (int)d0[3]; a.n2 = (int)d0[4];
    T3 b; b.s1 = d1[0]; b.s2 = d1[1]; b.s3 = d1[2]; b.n1 = (int)d1[3]; b.n2 = (int)d1[4];
    t3_merge(a, b);
    float* p = part + ((size_t)(m0 + tid) * 4 + bn) * 5;
    p[0] = a.s1; p[1] = a.s2; p[2] = a.s3; p[3] = (float)a.n1; p[4] = (float)a.n2;
  }
}

// Combine 4 n-slices per row; write idx, packed candidates, and worklists.
__global__ void vq_comb(const float* __restrict__ part, float* __restrict__ out_idx,
                        unsigned int* __restrict__ pk, int* __restrict__ wl1,
                        int* __restrict__ wl2, int* __restrict__ cnt) {
  int row = blockIdx.x * 256 + threadIdx.x;
  const float* p = part + (size_t)row * 20;
  T3 a; a.s1 = p[0]; a.s2 = p[1]; a.s3 = p[2]; a.n1 = (int)p[3]; a.n2 = (int)p[4];
#pragma unroll
  for (int j = 1; j < 4; ++j) {
    const float* q = p + j * 5;
    T3 b; b.s1 = q[0]; b.s2 = q[1]; b.s3 = q[2]; b.n1 = (int)q[3]; b.n2 = (int)q[4];
    t3_merge(a, b);
  }
  out_idx[row] = (float)a.n1;
  unsigned int f = 0;
  if (a.s2 - a.s1 < WINDOW) f = (a.s3 - a.s1 < WINDOW) ? 2u : 1u;
  pk[row] = (unsigned int)a.n1 | ((unsigned int)a.n2 << 10) | (f << 20);
  if (f == 1u) wl1[atomicAdd(&cnt[0], 1)] = row;
  if (f == 2u) wl2[atomicAdd(&cnt[1], 1)] = row;
}

// fp64 top-2 recheck with reference-exact final combine; one wave per row.
__global__ __launch_bounds__(256) void vq_recheckA(
    const float* __restrict__ z, const float* __restrict__ cb,
    const float* __restrict__ Aws, const float* __restrict__ Wws,
    const unsigned int* __restrict__ pk, const int* __restrict__ wl1,
    const int* __restrict__ cnt, float* __restrict__ out_idx)
{
  const int wave = threadIdx.x >> 6, lane = threadIdx.x & 63;
  const int gw = blockIdx.x * 4 + wave;
  const int c1 = cnt[0];
  for (int i = gw; i < c1; i += 2048) {
    int row = wl1[i];
    unsigned int p = pk[row];
    int n1 = p & 1023, n2 = (p >> 10) & 1023;
    int b = row >> 10, hw = row & 1023;
    const float* zr = z + (size_t)b * IMG_STRIDE + hw;
    const float* c1p = cb + (size_t)n1 * D_DIM;
    const float* c2p = cb + (size_t)n2 * D_DIM;
    double d1 = 0.0, d2 = 0.0;
#pragma unroll
    for (int j = 0; j < 8; ++j) {
      int c = lane + 64 * j;
      double zv = (double)zr[(size_t)c * HW];
      d1 += zv * (double)c1p[c];
      d2 += zv * (double)c2p[c];
    }
#pragma unroll
    for (int off = 32; off > 0; off >>= 1) {
      d1 += __shfl_down(d1, off);
      d2 += __shfl_down(d2, off);
    }
    if (lane == 0) {
      float A_ = Aws[row];
      float e1 = fadd32(fadd32(A_, -2.f * (float)d1), Wws[n1]);
      float e2 = fadd32(fadd32(A_, -2.f * (float)d2), Wws[n2]);
      int win = (e2 < e1 || (e2 == e1 && n2 < n1)) ? n2 : n1;
      out_idx[row] = (float)win;
    }
  }
}

// Full 1024-code fp64 rescan for flag==2 rows.
// R1 rewrite: 512 blocks (1 row/block typical), float4 cb loads, 4 independent
// fp64 accumulators. fp64 reassoc error ~5e-16 << fp32 ulp (~1e-9) of the
// scores, so the (float)dot rounding and all tie rules are unaffected.
__global__ __launch_bounds__(256) void vq_recheckB(
    const float* __restrict__ z, const float* __restrict__ cb,
    const float* __restrict__ Aws, const float* __restrict__ Wws,
    const int* __restrict__ wl2, const int* __restrict__ cnt,
    float* __restrict__ out_idx)
{
  __shared__ double zd[512];
  __shared__ float rd[256];
  __shared__ int rn[256];
  const int c2 = cnt[1];
  for (int t = blockIdx.x; t < c2; t += gridDim.x) {
    int row = wl2[t];
    int b = row >> 10, hw = row & 1023;
    const float* zr = z + (size_t)b * IMG_STRIDE + hw;
    for (int c = threadIdx.x; c < 512; c += 256) zd[c] = (double)zr[(size_t)c * HW];
    __syncthreads();
    float best = 3.4e38f; int bn_ = 0;
    float A_ = Aws[row];
    for (int k = 0; k < 4; ++k) {
      int n = k * 256 + threadIdx.x;
      const float* cn = cb + (size_t)n * D_DIM;
      double a0 = 0.0, a1 = 0.0, a2 = 0.0, a3 = 0.0;
#pragma unroll 8
      for (int c4 = 0; c4 < 128; ++c4) {
        float4 w4 = *(const float4*)(cn + 4 * c4);
        a0 += zd[4 * c4 + 0] * (double)w4.x;   // zd reads are broadcast (all
        a1 += zd[4 * c4 + 1] * (double)w4.y;   // lanes same addr) — no bank
        a2 += zd[4 * c4 + 2] * (double)w4.z;   // conflicts.
        a3 += zd[4 * c4 + 3] * (double)w4.w;
      }
      double dot = (a0 + a1) + (a2 + a3);
      float e = fadd32(fadd32(A_, -2.f * (float)dot), Wws[n]);
      if (e < best || (e == best && n < bn_)) { best = e; bn_ = n; }
    }
    rd[threadIdx.x] = best; rn[threadIdx.x] = bn_;
    __syncthreads();
    for (int s = 128; s > 0; s >>= 1) {
      if (threadIdx.x < s) {
        float eo = rd[threadIdx.x + s]; int no = rn[threadIdx.x + s];
        if (eo < rd[threadIdx.x] || (eo == rd[threadIdx.x] && no < rn[threadIdx.x])) {
          rd[threadIdx.x] = eo; rn[threadIdx.x] = no;
        }
      }
      __syncthreads();
    }
    if (threadIdx.x == 0) out_idx[row] = (float)rn[0];
    __syncthreads();
  }
}

// Final gather: out_q rows = codebook rows (contiguous; no inverse permute).
// Runs last — overwrites the zh scratch living in the out_q region.
__global__ __launch_bounds__(256) void vq_gather(const float* __restrict__ cb,
                                                 const float* __restrict__ out_idx,
                                                 float* __restrict__ out_q) {
  __shared__ int bidx[64];
  const int i0 = blockIdx.x * 64;
  if (threadIdx.x < 64) bidx[threadIdx.x] = (int)out_idx[i0 + threadIdx.x];
  __syncthreads();
  float* outp = out_q + (size_t)i0 * D_DIM;
  for (int j = 0; j < 32; ++j) {
    int f4i = j * 256 + threadIdx.x;
    int row = f4i >> 7, d4 = f4i & 127;
    float4 vv = *(const float4*)(cb + (size_t)bidx[row] * D_DIM + 4 * d4);
    *(float4*)(outp + 4 * f4i) = vv;
  }
}

extern "C" void kernel_launch(void* const* d_in, const int* in_sizes, int n_in,
                              void* d_out, int out_size, void* d_ws, size_t ws_size,
                              hipStream_t stream) {
  const float* z  = (const float*)d_in[0];
  const float* cb = (const float*)d_in[1];
  float* out_q   = (float*)d_out;
  float* out_idx = (float*)d_out + (size_t)M_ROWS * D_DIM;
  char* zh_b = (char*)d_out;                // out_q region doubles as zh scratch
  char* ws = (char*)d_ws;
  char* wh_b = ws + WH_OFF;
  float* Aws = (float*)(ws + A_OFF);
  float* Wws = (float*)(ws + W_OFF);
  unsigned int* pk = (unsigned int*)(ws + PK_OFF);
  float* part = (float*)(ws + PART_OFF);
  int* wl1 = (int*)(ws + WL1_OFF);
  int* wl2 = (int*)(ws + WL2_OFF);
  int* cnt = (int*)(ws + CNT_OFF);

  vq_prep    <<<128, 256, 0, stream>>>(z, Aws, zh_b);
  vq_prepw   <<<4, 256, 0, stream>>>(cb, Wws, wh_b, cnt);
  vq_score   <<<1024, 256, 0, stream>>>(zh_b, wh_b, Wws, part);
  vq_comb    <<<128, 256, 0, stream>>>(part, out_idx, pk, wl1, wl2, cnt);
  vq_recheckA<<<512, 256, 0, stream>>>(z, cb, Aws, Wws, pk, wl1, cnt, out_idx);
  vq_recheckB<<<512, 256, 0, stream>>>(z, cb, Aws, Wws, wl2, cnt, out_idx);
  vq_gather  <<<512, 256, 0, stream>>>(cb, out_idx, out_q);
}

// Round 4
// 353.784 us; speedup vs baseline: 1.1819x; 1.0631x over previous
//
#include <hip/hip_runtime.h>
#include <hip/hip_bf16.h>

// Problem constants
#define M_ROWS  32768   // B*H*W
#define D_DIM   512     // C == latent dim
#define K_CODES 1024
#define HW      1024
#define IMG_STRIDE (D_DIM * HW)   // 524288

// d_out scratch: zh swizzled bf16 (32 MB) lives in the out_q region until the
// final gather overwrites it. idx region (last 128 KB of d_out) is real output.
// ws layout (bytes):
#define WH_OFF   0u          // 1 MB   swizzled cb-hi bf16
#define A_OFF    1048576u    // 128 KB A[i] (numpy-pairwise)
#define W_OFF    1179648u    // 4 KB   W[n]
#define PK_OFF   1183744u    // 128 KB packed candidates/flags
#define PART_OFF 1312768u    // 2.62 MB per-(row,bn) top3 partials
#define WL1_OFF  3934208u    // 128 KB worklist flag==1
#define WL2_OFF  4065280u    // 128 KB worklist flag==2
#define CNT_OFF  4196352u    // 8 B    counters

// 1-term bf16 error: pairwise sigma ~4.3e-5 -> 7.5 sigma = 3.2e-4, plus fp32
// reorder/grid window 1.22e-4 -> 4.4e-4; pad to 5e-4.
#define WINDOW 5.0e-4f

// ---- exact RNE fp32 ops the compiler can't contract/reassociate ----
__device__ __forceinline__ float fmul32(float a, float b) {
  float r; asm volatile("v_mul_f32 %0, %1, %2" : "=v"(r) : "v"(a), "v"(b)); return r;
}
__device__ __forceinline__ float fadd32(float a, float b) {
  float r; asm volatile("v_add_f32 %0, %1, %2" : "=v"(r) : "v"(a), "v"(b)); return r;
}
__device__ __forceinline__ float pair8(const float* r) {
  return fadd32(fadd32(fadd32(r[0], r[1]), fadd32(r[2], r[3])),
                fadd32(fadd32(r[4], r[5]), fadd32(r[6], r[7])));
}

__device__ __forceinline__ unsigned short f2bf(float x) {
  __hip_bfloat16 h = __float2bfloat16(x);
  unsigned short u; __builtin_memcpy(&u, &h, 2); return u;
}

typedef __attribute__((ext_vector_type(8))) short b8;
typedef __attribute__((ext_vector_type(4))) float f4;

// top-3 tracking (values s1<=s2<=s3; indices for first two; first-index ties)
struct T3 { float s1, s2, s3; int n1, n2; };
__device__ __forceinline__ void t3_merge(T3& a, const T3& bb) {
  T3 x = a, y = bb;
  bool bf = (y.s1 < x.s1) || (y.s1 == x.s1 && y.n1 < x.n1);
  if (bf) { T3 t = x; x = y; y = t; }
  float rs2; int rn2; float rs3;
  bool c2 = (y.s1 < x.s2) || (y.s1 == x.s2 && y.n1 < x.n2);
  if (c2) { rs2 = y.s1; rn2 = y.n1; rs3 = fminf(x.s2, y.s2); }
  else    { rs2 = x.s2; rn2 = x.n2; rs3 = fminf(x.s3, y.s1); }
  a.s1 = x.s1; a.n1 = x.n1; a.s2 = rs2; a.n2 = rn2; a.s3 = rs3;
}

// ---------------------------------------------------------------------------
// Fused: A[i] = np.sum(z^2) (exact numpy fp32 pairwise order, round-3 code
// path untouched) + zh swizzled-bf16 emission. One pass over z.
// zh layout: [kc 16][mb 2048][q 4][m15 16][j 8] bf16.
__global__ __launch_bounds__(256) void vq_prep(const float* __restrict__ z,
                                               float* __restrict__ A,
                                               char* __restrict__ zh_b) {
  __shared__ float zs[4][64 * 68];
  const int wave = threadIdx.x >> 6, t = threadIdx.x & 63;
  const int i0 = blockIdx.x * 256 + wave * 64;
  const int b = i0 >> 10, hw0 = i0 & 1023;
  const float* zbase = z + (size_t)b * IMG_STRIDE + hw0;
  float* zsw = zs[wave];
  const int pos = i0 + t;
  const size_t mbase = (size_t)(pos >> 4) * 1024 + (size_t)(pos & 15) * 16;
  float r8[8], blk[4];
  alignas(16) unsigned short hs[8];
#pragma unroll
  for (int ch = 0; ch < 8; ++ch) {
    __syncthreads();
    {
      const int l = t & 15, j0 = t >> 4;
#pragma unroll
      for (int jj = 0; jj < 16; ++jj) {
        int j = j0 * 16 + jj;
        float4 vv = *(const float4*)(zbase + (size_t)(ch * 64 + j) * HW + 4 * l);
        *(float4*)(zsw + j * 68 + 4 * l) = vv;
      }
    }
    __syncthreads();
#pragma unroll
    for (int j = 0; j < 64; ++j) {
      const int c = ch * 64 + j;
      float v = zsw[j * 68 + t];
      hs[j & 7] = f2bf(v);
      if ((j & 7) == 7) {
        const int kc = c >> 5, q = (c >> 3) & 3;
        *(uint4*)(zh_b + (size_t)kc * 2097152 + q * 256 + mbase) = *(uint4*)hs;
      }
      float pq = fmul32(v, v);
      const int k = c & 7, m = c & 127;
      if (m < 8) r8[k] = pq;
      else       r8[k] = fadd32(r8[k], pq);
      if (m == 127) blk[c >> 7] = pair8(r8);
    }
  }
  A[pos] = fadd32(fadd32(blk[0], blk[1]), fadd32(blk[2], blk[3]));
}

// Fused: W[n] = np.sum(cb^2) (exact pairwise order) + wh swizzled emission.
// wh layout: [kc 16][nb 64][q 4][n15 16][j 8] bf16. Also zeroes counters.
__global__ void vq_prepw(const float* __restrict__ cb, float* __restrict__ W,
                         char* __restrict__ wh_b, int* __restrict__ cnt) {
  if (blockIdx.x == 0 && threadIdx.x < 2) cnt[threadIdx.x] = 0;
  const int n = blockIdx.x * 256 + threadIdx.x;
  const float* wp = cb + (size_t)n * D_DIM;
  const size_t nbase = (size_t)(n >> 4) * 1024 + (size_t)(n & 15) * 16;
  float r8[8], blk[4];
  alignas(16) unsigned short hs[8];
#pragma unroll
  for (int bb = 0; bb < 4; ++bb) {
#pragma unroll
    for (int g = 0; g < 16; ++g) {
      float vv[8];
#pragma unroll
      for (int k = 0; k < 8; ++k) vv[k] = wp[bb * 128 + g * 8 + k];
#pragma unroll
      for (int k = 0; k < 8; ++k) {
        float pq = fmul32(vv[k], vv[k]);
        if (g == 0) r8[k] = pq;
        else        r8[k] = fadd32(r8[k], pq);
        hs[k] = f2bf(vv[k]);
      }
      const int kc = bb * 4 + (g >> 2), q = g & 3;
      *(uint4*)(wh_b + (size_t)kc * 65536 + q * 256 + nbase) = *(uint4*)hs;
    }
    blk[bb] = pair8(r8);
  }
  W[n] = fadd32(fadd32(blk[0], blk[1]), fadd32(blk[2], blk[3]));
}

// ---------------------------------------------------------------------------
// 1-term MFMA scoring: M ~= zh·wh (bf16, fp32 acc); s = W - 2M.
// Block tile 128 pos x 256 n; wave tile 64x128 (4x8 of 16x16x32).
// R3: NO LDS in the K-loop. R2's dbuf was null because __syncthreads drains
// vmcnt(0) — global_load_lds prefetch can't survive a barrier (m99/m100).
// The zh/wh layouts make every MFMA fragment a contiguous 16B at lane*16, so
// fragments load straight to VGPRs (global_load_dwordx4), depth-1 register
// double-buffer, zero barriers in the loop -> counted vmcnt waits, loads in
// flight across iterations, free-running waves. Same MFMA order -> bit-equal.
__global__ __launch_bounds__(256, 2) void vq_score(
    const char* __restrict__ zh_b, const char* __restrict__ wh_b,
    const float* __restrict__ Wws, float* __restrict__ part)
{
  __shared__ float red[1280];   // [128 rows][2 wc][5] epilogue reduce
  const int tid = threadIdx.x;
  const int lane = tid & 63, wave = tid >> 6;
  const int wr = wave >> 1, wc = wave & 1;
  const int bm = blockIdx.x & 255, bn = blockIdx.x >> 8;
  const int m0 = bm * 128, n0 = bn * 256;

  f4 acc[4][8];
#pragma unroll
  for (int r = 0; r < 4; ++r)
#pragma unroll
    for (int v = 0; v < 8; ++v) acc[r][v] = (f4)(0.0f);

  // per-wave fragment base pointers (identical bytes to the old LDS path):
  // ah(r,kc) = zh[kc*2M + bm*8192 + (wr*4+r)*1024 + lane*16 ..+16)
  // bh(v,kc) = wh[kc*64K + bn*16384 + (wc*8+v)*1024 + lane*16 ..+16)
  const char* gA_w = zh_b + (size_t)bm * 8192 + (size_t)(wr * 4) * 1024 + (size_t)lane * 16;
  const char* gB_w = wh_b + (size_t)bn * 16384 + (size_t)(wc * 8) * 1024 + (size_t)lane * 16;

  b8 ar[2][4], br[2][8];
#pragma unroll
  for (int r = 0; r < 4; ++r)
    ar[0][r] = *(const b8*)(gA_w + (size_t)r * 1024);
#pragma unroll
  for (int v = 0; v < 8; ++v)
    br[0][v] = *(const b8*)(gB_w + (size_t)v * 1024);

#pragma unroll
  for (int kc = 0; kc < 16; ++kc) {
    const int cur = kc & 1, nxt = cur ^ 1;
    if (kc + 1 < 16) {
      const char* gA = gA_w + (size_t)(kc + 1) * 2097152;
      const char* gB = gB_w + (size_t)(kc + 1) * 65536;
#pragma unroll
      for (int r = 0; r < 4; ++r) ar[nxt][r] = *(const b8*)(gA + (size_t)r * 1024);
#pragma unroll
      for (int v = 0; v < 8; ++v) br[nxt][v] = *(const b8*)(gB + (size_t)v * 1024);
    }
#pragma unroll
    for (int r = 0; r < 4; ++r) {
#pragma unroll
      for (int v = 0; v < 8; ++v)
        acc[r][v] = __builtin_amdgcn_mfma_f32_16x16x32_bf16(ar[cur][r], br[cur][v],
                                                            acc[r][v], 0, 0, 0);
    }
  }

  // epilogue: s = W - 2M; per-row top-3 across this block's 256 n
  const int l15 = lane & 15, quad = lane >> 4;
  float sW[8];
#pragma unroll
  for (int v = 0; v < 8; ++v) sW[v] = Wws[n0 + wc * 128 + v * 16 + l15];

#pragma unroll
  for (int r = 0; r < 4; ++r) {
#pragma unroll
    for (int reg = 0; reg < 4; ++reg) {
      T3 t; t.s1 = t.s2 = t.s3 = 3.4e38f; t.n1 = 0; t.n2 = 0;
#pragma unroll
      for (int v = 0; v < 8; ++v) {
        float s = fmaf(-2.f, acc[r][v][reg], sW[v]);
        int n = n0 + wc * 128 + v * 16 + l15;
        if (s < t.s1)      { t.s3 = t.s2; t.s2 = t.s1; t.n2 = t.n1; t.s1 = s; t.n1 = n; }
        else if (s < t.s2) { t.s3 = t.s2; t.s2 = s; t.n2 = n; }
        else if (s < t.s3) { t.s3 = s; }
      }
#pragma unroll
      for (int m = 1; m <= 8; m <<= 1) {   // butterfly within 16-lane quad
        T3 o;
        o.s1 = __shfl_xor(t.s1, m); o.s2 = __shfl_xor(t.s2, m); o.s3 = __shfl_xor(t.s3, m);
        o.n1 = __shfl_xor(t.n1, m); o.n2 = __shfl_xor(t.n2, m);
        t3_merge(t, o);
      }
      if (l15 == 0) {
        int row = wr * 64 + r * 16 + quad * 4 + reg;
        float* d = red + (row * 2 + wc) * 5;
        d[0] = t.s1; d[1] = t.s2; d[2] = t.s3; d[3] = (float)t.n1; d[4] = (float)t.n2;
      }
    }
  }
  __syncthreads();
  if (tid < 128) {
    const float* d0 = red + (tid * 2) * 5;
    const float* d1 = red + (tid * 2 + 1) * 5;
    T3 a; a.s1 = d0[0]; a.s2 = d0[1]; a.s3 = d0[2]; a.n1 = (int)d0[3]; a.n2 = (int)d0[4];
    T3 b; b.s1 = d1[0]; b.s2 = d1[1]; b.s3 = d1[2]; b.n1 = (int)d1[3]; b.n2 = (int)d1[4];
    t3_merge(a, b);
    float* p = part + ((size_t)(m0 + tid) * 4 + bn) * 5;
    p[0] = a.s1; p[1] = a.s2; p[2] = a.s3; p[3] = (float)a.n1; p[4] = (float)a.n2;
  }
}

// Combine 4 n-slices per row; write idx, packed candidates, and worklists.
__global__ void vq_comb(const float* __restrict__ part, float* __restrict__ out_idx,
                        unsigned int* __restrict__ pk, int* __restrict__ wl1,
                        int* __restrict__ wl2, int* __restrict__ cnt) {
  int row = blockIdx.x * 256 + threadIdx.x;
  const float* p = part + (size_t)row * 20;
  T3 a; a.s1 = p[0]; a.s2 = p[1]; a.s3 = p[2]; a.n1 = (int)p[3]; a.n2 = (int)p[4];
#pragma unroll
  for (int j = 1; j < 4; ++j) {
    const float* q = p + j * 5;
    T3 b; b.s1 = q[0]; b.s2 = q[1]; b.s3 = q[2]; b.n1 = (int)q[3]; b.n2 = (int)q[4];
    t3_merge(a, b);
  }
  out_idx[row] = (float)a.n1;
  unsigned int f = 0;
  if (a.s2 - a.s1 < WINDOW) f = (a.s3 - a.s1 < WINDOW) ? 2u : 1u;
  pk[row] = (unsigned int)a.n1 | ((unsigned int)a.n2 << 10) | (f << 20);
  if (f == 1u) wl1[atomicAdd(&cnt[0], 1)] = row;
  if (f == 2u) wl2[atomicAdd(&cnt[1], 1)] = row;
}

// fp64 top-2 recheck with reference-exact final combine; one wave per row.
__global__ __launch_bounds__(256) void vq_recheckA(
    const float* __restrict__ z, const float* __restrict__ cb,
    const float* __restrict__ Aws, const float* __restrict__ Wws,
    const unsigned int* __restrict__ pk, const int* __restrict__ wl1,
    const int* __restrict__ cnt, float* __restrict__ out_idx)
{
  const int wave = threadIdx.x >> 6, lane = threadIdx.x & 63;
  const int gw = blockIdx.x * 4 + wave;
  const int c1 = cnt[0];
  for (int i = gw; i < c1; i += 2048) {
    int row = wl1[i];
    unsigned int p = pk[row];
    int n1 = p & 1023, n2 = (p >> 10) & 1023;
    int b = row >> 10, hw = row & 1023;
    const float* zr = z + (size_t)b * IMG_STRIDE + hw;
    const float* c1p = cb + (size_t)n1 * D_DIM;
    const float* c2p = cb + (size_t)n2 * D_DIM;
    double d1 = 0.0, d2 = 0.0;
#pragma unroll
    for (int j = 0; j < 8; ++j) {
      int c = lane + 64 * j;
      double zv = (double)zr[(size_t)c * HW];
      d1 += zv * (double)c1p[c];
      d2 += zv * (double)c2p[c];
    }
#pragma unroll
    for (int off = 32; off > 0; off >>= 1) {
      d1 += __shfl_down(d1, off);
      d2 += __shfl_down(d2, off);
    }
    if (lane == 0) {
      float A_ = Aws[row];
      float e1 = fadd32(fadd32(A_, -2.f * (float)d1), Wws[n1]);
      float e2 = fadd32(fadd32(A_, -2.f * (float)d2), Wws[n2]);
      int win = (e2 < e1 || (e2 == e1 && n2 < n1)) ? n2 : n1;
      out_idx[row] = (float)win;
    }
  }
}

// Full 1024-code fp64 rescan for flag==2 rows.
// R1 rewrite: 512 blocks (1 row/block typical), float4 cb loads, 4 independent
// fp64 accumulators. fp64 reassoc error ~5e-16 << fp32 ulp (~1e-9) of the
// scores, so the (float)dot rounding and all tie rules are unaffected.
__global__ __launch_bounds__(256) void vq_recheckB(
    const float* __restrict__ z, const float* __restrict__ cb,
    const float* __restrict__ Aws, const float* __restrict__ Wws,
    const int* __restrict__ wl2, const int* __restrict__ cnt,
    float* __restrict__ out_idx)
{
  __shared__ double zd[512];
  __shared__ float rd[256];
  __shared__ int rn[256];
  const int c2 = cnt[1];
  for (int t = blockIdx.x; t < c2; t += gridDim.x) {
    int row = wl2[t];
    int b = row >> 10, hw = row & 1023;
    const float* zr = z + (size_t)b * IMG_STRIDE + hw;
    for (int c = threadIdx.x; c < 512; c += 256) zd[c] = (double)zr[(size_t)c * HW];
    __syncthreads();
    float best = 3.4e38f; int bn_ = 0;
    float A_ = Aws[row];
    for (int k = 0; k < 4; ++k) {
      int n = k * 256 + threadIdx.x;
      const float* cn = cb + (size_t)n * D_DIM;
      double a0 = 0.0, a1 = 0.0, a2 = 0.0, a3 = 0.0;
#pragma unroll 8
      for (int c4 = 0; c4 < 128; ++c4) {
        float4 w4 = *(const float4*)(cn + 4 * c4);
        a0 += zd[4 * c4 + 0] * (double)w4.x;   // zd reads are broadcast (all
        a1 += zd[4 * c4 + 1] * (double)w4.y;   // lanes same addr) — no bank
        a2 += zd[4 * c4 + 2] * (double)w4.z;   // conflicts.
        a3 += zd[4 * c4 + 3] * (double)w4.w;
      }
      double dot = (a0 + a1) + (a2 + a3);
      float e = fadd32(fadd32(A_, -2.f * (float)dot), Wws[n]);
      if (e < best || (e == best && n < bn_)) { best = e; bn_ = n; }
    }
    rd[threadIdx.x] = best; rn[threadIdx.x] = bn_;
    __syncthreads();
    for (int s = 128; s > 0; s >>= 1) {
      if (threadIdx.x < s) {
        float eo = rd[threadIdx.x + s]; int no = rn[threadIdx.x + s];
        if (eo < rd[threadIdx.x] || (eo == rd[threadIdx.x] && no < rn[threadIdx.x])) {
          rd[threadIdx.x] = eo; rn[threadIdx.x] = no;
        }
      }
      __syncthreads();
    }
    if (threadIdx.x == 0) out_idx[row] = (float)rn[0];
    __syncthreads();
  }
}

// Final gather: out_q rows = codebook rows (contiguous; no inverse permute).
// Runs last — overwrites the zh scratch living in the out_q region.
__global__ __launch_bounds__(256) void vq_gather(const float* __restrict__ cb,
                                                 const float* __restrict__ out_idx,
                                                 float* __restrict__ out_q) {
  __shared__ int bidx[64];
  const int i0 = blockIdx.x * 64;
  if (threadIdx.x < 64) bidx[threadIdx.x] = (int)out_idx[i0 + threadIdx.x];
  __syncthreads();
  float* outp = out_q + (size_t)i0 * D_DIM;
  for (int j = 0; j < 32; ++j) {
    int f4i = j * 256 + threadIdx.x;
    int row = f4i >> 7, d4 = f4i & 127;
    float4 vv = *(const float4*)(cb + (size_t)bidx[row] * D_DIM + 4 * d4);
    *(float4*)(outp + 4 * f4i) = vv;
  }
}

extern "C" void kernel_launch(void* const* d_in, const int* in_sizes, int n_in,
                              void* d_out, int out_size, void* d_ws, size_t ws_size,
                              hipStream_t stream) {
  const float* z  = (const float*)d_in[0];
  const float* cb = (const float*)d_in[1];
  float* out_q   = (float*)d_out;
  float* out_idx = (float*)d_out + (size_t)M_ROWS * D_DIM;
  char* zh_b = (char*)d_out;                // out_q region doubles as zh scratch
  char* ws = (char*)d_ws;
  char* wh_b = ws + WH_OFF;
  float* Aws = (float*)(ws + A_OFF);
  float* Wws = (float*)(ws + W_OFF);
  unsigned int* pk = (unsigned int*)(ws + PK_OFF);
  float* part = (float*)(ws + PART_OFF);
  int* wl1 = (int*)(ws + WL1_OFF);
  int* wl2 = (int*)(ws + WL2_OFF);
  int* cnt = (int*)(ws + CNT_OFF);

  vq_prep    <<<128, 256, 0, stream>>>(z, Aws, zh_b);
  vq_prepw   <<<4, 256, 0, stream>>>(cb, Wws, wh_b, cnt);
  vq_score   <<<1024, 256, 0, stream>>>(zh_b, wh_b, Wws, part);
  vq_comb    <<<128, 256, 0, stream>>>(part, out_idx, pk, wl1, wl2, cnt);
  vq_recheckA<<<512, 256, 0, stream>>>(z, cb, Aws, Wws, pk, wl1, cnt, out_idx);
  vq_recheckB<<<512, 256, 0, stream>>>(z, cb, Aws, Wws, wl2, cnt, out_idx);
  vq_gather  <<<512, 256, 0, stream>>>(cb, out_idx, out_q);
}